// Round 15
// baseline (176.333 us; speedup 1.0000x reference)
//
#include <hip/hip_runtime.h>
#include <math.h>

// Problem constants
#define KP   10      // prototypes per side
#define CC   768     // channels
#define NB   8       // batch
#define HW   4096    // 64*64
#define STOT 32768   // NB*HW
#define NS   12      // N_SAMPLES
#define NBLK 256     // k_scores blocks (128 px each)

// Workspace layout (float offsets): only candidates now
#define WS_CAND  0       // 2 sides x 256 blocks x 12 u64

typedef unsigned long long ull;
typedef float f2v __attribute__((ext_vector_type(2)));

// packed 2-wide fma (v_pk_fma_f32); per-component order identical to scalar fmaf
__device__ __forceinline__ f2v fma2(f2v a, float b, f2v c) {
#if __has_builtin(__builtin_elementwise_fma)
    f2v bb = b;
    return __builtin_elementwise_fma(a, bb, c);
#else
    f2v r; r.x = fmaf(a.x, b, c.x); r.y = fmaf(a.y, b, c.y); return r;
#endif
}

// Order-preserving float->uint map, packed with ~index: exact
// (value desc, index asc) under unsigned max; unique per pixel; 0 = empty.
__device__ __forceinline__ ull pack_key(float v, int idx) {
    unsigned u = __float_as_uint(v);
    u ^= (unsigned)((int)u >> 31) | 0x80000000u;
    return ((ull)u << 32) | (ull)(0xFFFFFFFFu - (unsigned)idx);
}

// ---------------- K1: scores + per-block top-12 candidates ----------------
// (unchanged from R13: packed-f32 accumulators, LDS protos, nt F loads,
//  depth-2 prefetch, barrier-free per-block selection)
__global__ __launch_bounds__(1024) void k_scores(const float* __restrict__ fg,
                                                 const float* __restrict__ bg,
                                                 const float* __restrict__ F,
                                                 const float* __restrict__ M,
                                                 ull* __restrict__ cand) {
    __shared__ float pl[20 * CC];           // 61440 B
    __shared__ float part[8][64][2][21];    // 86016 B
    __shared__ ull kfl[128], kbl[128];      // 2048 B

    const int tid  = threadIdx.x;
    const int w    = __builtin_amdgcn_readfirstlane(tid >> 6);  // wave 0..15
    const int lane = tid & 63;
    const int b    = blockIdx.x;            // 0..255
    const int n    = b >> 5;                // 32 blocks per image
    const int hwb  = (b & 31) * 128 + lane * 2;
    const float* fp = F + ((size_t)n * CC) * HW + hwb;
    const int cbase = w * 48;

    f2v fnA[8], fnB[8];
#pragma unroll
    for (int j = 0; j < 8; ++j)
        fnA[j] = __builtin_nontemporal_load((const f2v*)(fp + (size_t)(cbase + j) * HW));
#pragma unroll
    for (int j = 0; j < 8; ++j)
        fnB[j] = __builtin_nontemporal_load((const f2v*)(fp + (size_t)(cbase + 8 + j) * HW));

    for (int i = tid; i < KP * CC; i += 1024) {
        pl[i]           = fg[i];
        pl[KP * CC + i] = bg[i];
    }
    __syncthreads();

    f2v afg[KP], abg[KP], n2;
#pragma unroll
    for (int k = 0; k < KP; ++k) { afg[k] = 0.f; abg[k] = 0.f; }
    n2 = 0.f;

    for (int c0 = 0; c0 < 48; c0 += 8) {
        f2v f[8];
#pragma unroll
        for (int j = 0; j < 8; ++j) { f[j] = fnA[j]; fnA[j] = fnB[j]; }
        if (c0 + 16 < 48) {
#pragma unroll
            for (int j = 0; j < 8; ++j)
                fnB[j] = __builtin_nontemporal_load((const f2v*)(fp + (size_t)(cbase + c0 + 16 + j) * HW));
        }

#pragma unroll
        for (int k = 0; k < KP; ++k) {
            const float4* pq = (const float4*)&pl[k * CC + cbase + c0];
            float4 a = pq[0], c = pq[1];
            f2v acc = afg[k];
            acc = fma2(f[0], a.x, acc); acc = fma2(f[1], a.y, acc);
            acc = fma2(f[2], a.z, acc); acc = fma2(f[3], a.w, acc);
            acc = fma2(f[4], c.x, acc); acc = fma2(f[5], c.y, acc);
            acc = fma2(f[6], c.z, acc); acc = fma2(f[7], c.w, acc);
            afg[k] = acc;
        }
#pragma unroll
        for (int k = 0; k < KP; ++k) {
            const float4* pq = (const float4*)&pl[(KP + k) * CC + cbase + c0];
            float4 a = pq[0], c = pq[1];
            f2v acc = abg[k];
            acc = fma2(f[0], a.x, acc); acc = fma2(f[1], a.y, acc);
            acc = fma2(f[2], a.z, acc); acc = fma2(f[3], a.w, acc);
            acc = fma2(f[4], c.x, acc); acc = fma2(f[5], c.y, acc);
            acc = fma2(f[6], c.z, acc); acc = fma2(f[7], c.w, acc);
            abg[k] = acc;
        }
#pragma unroll
        for (int j = 0; j < 8; ++j) {
#if __has_builtin(__builtin_elementwise_fma)
            n2 = __builtin_elementwise_fma(f[j], f[j], n2);
#else
            n2.x = fmaf(f[j].x, f[j].x, n2.x); n2.y = fmaf(f[j].y, f[j].y, n2.y);
#endif
        }
    }

    if (w >= 8) {
#pragma unroll
        for (int k = 0; k < KP; ++k) {
            part[w - 8][lane][0][k]      = afg[k].x; part[w - 8][lane][1][k]      = afg[k].y;
            part[w - 8][lane][0][10 + k] = abg[k].x; part[w - 8][lane][1][10 + k] = abg[k].y;
        }
        part[w - 8][lane][0][20] = n2.x; part[w - 8][lane][1][20] = n2.y;
    }
    __syncthreads();
    if (w < 8) {
#pragma unroll
        for (int k = 0; k < KP; ++k) {
            part[w][lane][0][k]      += afg[k].x; part[w][lane][1][k]      += afg[k].y;
            part[w][lane][0][10 + k] += abg[k].x; part[w][lane][1][10 + k] += abg[k].y;
        }
        part[w][lane][0][20] += n2.x; part[w][lane][1][20] += n2.y;
    }
    __syncthreads();

    if (tid < 128) {
        const int lane2 = tid >> 1, j = tid & 1;
        float vals[21];
#pragma unroll
        for (int q = 0; q < 21; ++q) {
            float acc = 0.f;
#pragma unroll
            for (int ss = 0; ss < 8; ++ss) acc += part[ss][lane2][j][q];
            vals[q] = acc;
        }
        float mfg = vals[0], mbg = vals[10];
#pragma unroll
        for (int k = 1; k < KP; ++k) { mfg = fmaxf(mfg, vals[k]); mbg = fmaxf(mbg, vals[10 + k]); }
        float nc = fmaxf(sqrtf(vals[20]), 1e-8f);
        int sp = b * 128 + tid;
        float m = fminf(fmaxf(M[sp], 0.f), 1.f);
        kfl[tid] = pack_key((1.f - mfg / nc) * m, sp);
        kbl[tid] = pack_key((1.f - mbg / nc) * (1.f - m), sp);
    }
    __syncthreads();

    if (w == 0) {
        ull k0 = kfl[lane], k1 = kfl[64 + lane];
        for (int r = 0; r < NS; ++r) {
            ull bk = (k0 > k1) ? k0 : k1;
#pragma unroll
            for (int m2 = 1; m2 < 64; m2 <<= 1) {
                ull o = __shfl_xor(bk, m2, 64);
                bk = (o > bk) ? o : bk;
            }
            if (lane == 0) cand[b * NS + r] = bk;
            if (k0 == bk) k0 = 0ull;
            if (k1 == bk) k1 = 0ull;
        }
    } else if (w == 1) {
        ull k0 = kbl[lane], k1 = kbl[64 + lane];
        for (int r = 0; r < NS; ++r) {
            ull bk = (k0 > k1) ? k0 : k1;
#pragma unroll
            for (int m2 = 1; m2 < 64; m2 <<= 1) {
                ull o = __shfl_xor(bk, m2, 64);
                bk = (o > bk) ? o : bk;
            }
            if (lane == 0) cand[NBLK * NS + b * NS + r] = bk;
            if (k0 == bk) k0 = 0ull;
            if (k1 == bk) k1 = 0ull;
        }
    }
}

// ---- K2: single-block tail: merge both sides + gather + normalize +
//      dual-side refine (R13 structure) + blend-out + in-LDS loss ----
__global__ __launch_bounds__(1024) void k_tail(const ull* __restrict__ cand,
                                               const float* __restrict__ F,
                                               const float* __restrict__ fg,
                                               const float* __restrict__ bg,
                                               float* __restrict__ out) {
    __shared__ float fe[2 * NS * CC];   // 73728 B  (side-major rows)
    __shared__ float pl[2 * KP * CC];   // 61440 B  (p0; later refined protos)
    __shared__ int   seli[2 * NS];
    __shared__ float dots[2][NS][KP];
    __shared__ int   assign[2][NS];
    __shared__ float dots3[NS * 30];
    __shared__ float mp[NS], mn[NS], infon[NS];

    const int tid  = threadIdx.x;
    const int w    = __builtin_amdgcn_readfirstlane(tid >> 6);  // 0..15
    const int lane = tid & 63;

    // ---- merge: wave 0 = fg, wave 1 = bg (parallel, barrier-free scans);
    //      waves 2..15 stage both proto sets into LDS ----
    if (w < 2) {
        const ull* cs = cand + w * (NBLK * NS);
        ull tv[NS];
#pragma unroll
        for (int q = 0; q < NS; ++q) tv[q] = 0ull;
        for (int c = 0; c < 48; ++c) {               // 3072 keys / 64 lanes
            ull key = cs[c * 64 + lane];
            if (key > tv[NS - 1]) {
#pragma unroll
                for (int q = NS - 1; q >= 1; --q) {
                    bool shift = key > tv[q - 1];
                    bool here  = !shift && (key > tv[q]);
                    tv[q] = shift ? tv[q - 1] : (here ? key : tv[q]);
                }
                if (key > tv[0]) tv[0] = key;
            }
        }
        for (int r = 0; r < NS; ++r) {
            ull bk = tv[0];
#pragma unroll
            for (int m2 = 1; m2 < 64; m2 <<= 1) {
                ull o = __shfl_xor(bk, m2, 64);
                bk = (o > bk) ? o : bk;
            }
            if (lane == 0) seli[w * NS + r] = (int)(0xFFFFFFFFu - (unsigned)(bk & 0xFFFFFFFFull));
            bool win = (tv[0] == bk);                // keys unique -> one lane
#pragma unroll
            for (int q = 0; q < NS - 1; ++q) tv[q] = win ? tv[q + 1] : tv[q];
            tv[NS - 1] = win ? 0ull : tv[NS - 1];
        }
    } else {
        for (int i = tid - 128; i < 2 * KP * CC; i += 896)
            pl[i] = (i < KP * CC) ? fg[i] : bg[i - KP * CC];
    }
    __syncthreads();

    // ---- gather 24 rows x 768 channels into LDS ----
    for (int i = tid; i < 2 * NS * CC; i += 1024) {
        int row = i / CC, c = i - row * CC;
        int sp = seli[row];
        fe[i] = F[((size_t)(sp >> 12) * CC + c) * HW + (sp & 4095)];
    }
    __syncthreads();

    // ---- row-normalize in place (24 rows over 16 waves) ----
    for (int row = w; row < 2 * NS; row += 16) {
        float ssq = 0.f;
#pragma unroll
        for (int j = 0; j < 12; ++j) { float v = fe[row * CC + j * 64 + lane]; ssq = fmaf(v, v, ssq); }
#pragma unroll
        for (int m2 = 1; m2 < 64; m2 <<= 1) ssq += __shfl_xor(ssq, m2, 64);
        float inv = 1.f / fmaxf(sqrtf(ssq), 1e-8f);
#pragma unroll
        for (int j = 0; j < 12; ++j) fe[row * CC + j * 64 + lane] *= inv;
    }
    __syncthreads();

    // ---- dual-side refinement: proto-wave k handles sides 0 and 1 with ILP ----
    float4 p[2][3];
#pragma unroll
    for (int sd = 0; sd < 2; ++sd)
#pragma unroll
        for (int j4 = 0; j4 < 3; ++j4) p[sd][j4] = make_float4(0.f, 0.f, 0.f, 0.f);
    if (w < KP) {
#pragma unroll
        for (int sd = 0; sd < 2; ++sd)
#pragma unroll
            for (int j4 = 0; j4 < 3; ++j4)
                p[sd][j4] = *(const float4*)&pl[(sd * KP + w) * CC + j4 * 256 + lane * 4];
    }

    for (int it = 0; it < 10; ++it) {
        float step = 0.1f / (1.0f + 0.5f * (float)it);

        if (w < KP) {
            float d[2][NS];
#pragma unroll
            for (int sd = 0; sd < 2; ++sd)
#pragma unroll
                for (int s = 0; s < NS; ++s) d[sd][s] = 0.f;
#pragma unroll
            for (int sd = 0; sd < 2; ++sd) {
#pragma unroll
                for (int j4 = 0; j4 < 3; ++j4) {
                    float4 pv = p[sd][j4];
#pragma unroll
                    for (int s = 0; s < NS; ++s) {
                        float4 fv = *(const float4*)&fe[(sd * NS + s) * CC + j4 * 256 + lane * 4];
                        d[sd][s] = fmaf(fv.x, pv.x, d[sd][s]);
                        d[sd][s] = fmaf(fv.y, pv.y, d[sd][s]);
                        d[sd][s] = fmaf(fv.z, pv.z, d[sd][s]);
                        d[sd][s] = fmaf(fv.w, pv.w, d[sd][s]);
                    }
                }
            }
#pragma unroll
            for (int sd = 0; sd < 2; ++sd)
#pragma unroll
                for (int s = 0; s < NS; ++s) {
#pragma unroll
                    for (int m2 = 1; m2 < 64; m2 <<= 1) d[sd][s] += __shfl_xor(d[sd][s], m2, 64);
                }
            if (lane == 0) {
#pragma unroll
                for (int sd = 0; sd < 2; ++sd)
#pragma unroll
                    for (int s = 0; s < NS; ++s) dots[sd][s][w] = d[sd][s];
            }
        }
        __syncthreads();

        if (tid < 2 * NS) {
            int sd = tid / NS, s = tid - sd * NS;
            float bv = dots[sd][s][0]; int bk = 0;
#pragma unroll
            for (int kk = 1; kk < KP; ++kk) { float v = dots[sd][s][kk]; if (v > bv) { bv = v; bk = kk; } }
            assign[sd][s] = bk;
        }
        __syncthreads();

        if (w < KP) {
#pragma unroll
            for (int sd = 0; sd < 2; ++sd) {
                int a[NS]; int cnt = 0;
#pragma unroll
                for (int s = 0; s < NS; ++s) { a[s] = assign[sd][s]; cnt += (a[s] == w) ? 1 : 0; }
                if (cnt > 0) {
                    float4 mac[3];
#pragma unroll
                    for (int j4 = 0; j4 < 3; ++j4) mac[j4] = make_float4(0.f, 0.f, 0.f, 0.f);
#pragma unroll
                    for (int s = 0; s < NS; ++s) {
                        if (a[s] == w) {   // wave-uniform branch
#pragma unroll
                            for (int j4 = 0; j4 < 3; ++j4) {
                                float4 fv = *(const float4*)&fe[(sd * NS + s) * CC + j4 * 256 + lane * 4];
                                mac[j4].x += fv.x; mac[j4].y += fv.y; mac[j4].z += fv.z; mac[j4].w += fv.w;
                            }
                        }
                    }
                    float fcnt = (float)cnt;
                    float4 v[3]; float ss = 0.f;
#pragma unroll
                    for (int j4 = 0; j4 < 3; ++j4) {
                        v[j4].x = (1.0f - step) * p[sd][j4].x + step * (mac[j4].x / fcnt);
                        v[j4].y = (1.0f - step) * p[sd][j4].y + step * (mac[j4].y / fcnt);
                        v[j4].z = (1.0f - step) * p[sd][j4].z + step * (mac[j4].z / fcnt);
                        v[j4].w = (1.0f - step) * p[sd][j4].w + step * (mac[j4].w / fcnt);
                        ss = fmaf(v[j4].x, v[j4].x, ss);
                        ss = fmaf(v[j4].y, v[j4].y, ss);
                        ss = fmaf(v[j4].z, v[j4].z, ss);
                        ss = fmaf(v[j4].w, v[j4].w, ss);
                    }
#pragma unroll
                    for (int m2 = 1; m2 < 64; m2 <<= 1) ss += __shfl_xor(ss, m2, 64);
                    float inv = 1.f / fmaxf(sqrtf(ss), 1e-8f);
#pragma unroll
                    for (int j4 = 0; j4 < 3; ++j4) {
                        p[sd][j4].x = v[j4].x * inv; p[sd][j4].y = v[j4].y * inv;
                        p[sd][j4].z = v[j4].z * inv; p[sd][j4].w = v[j4].w * inv;
                    }
                }
            }
        }
    }

    // ---- blend-out + stash refined protos over pl ----
    if (w < KP) {
#pragma unroll
        for (int sd = 0; sd < 2; ++sd) {
            float* prow = &pl[(sd * KP + w) * CC];
            float4 vv[3]; float ss2 = 0.f;
#pragma unroll
            for (int j4 = 0; j4 < 3; ++j4) {
                float4 pz = *(const float4*)&prow[j4 * 256 + lane * 4];
                vv[j4].x = 0.7f * pz.x + 0.3f * p[sd][j4].x;
                vv[j4].y = 0.7f * pz.y + 0.3f * p[sd][j4].y;
                vv[j4].z = 0.7f * pz.z + 0.3f * p[sd][j4].z;
                vv[j4].w = 0.7f * pz.w + 0.3f * p[sd][j4].w;
                ss2 = fmaf(vv[j4].x, vv[j4].x, ss2);
                ss2 = fmaf(vv[j4].y, vv[j4].y, ss2);
                ss2 = fmaf(vv[j4].z, vv[j4].z, ss2);
                ss2 = fmaf(vv[j4].w, vv[j4].w, ss2);
            }
#pragma unroll
            for (int m2 = 1; m2 < 64; m2 <<= 1) ss2 += __shfl_xor(ss2, m2, 64);
            float inv2 = 1.f / fmaxf(sqrtf(ss2), 1e-8f);
            float* orow = out + 1 + (sd * KP + w) * CC;
#pragma unroll
            for (int j4 = 0; j4 < 3; ++j4) {
                float4 o4;
                o4.x = vv[j4].x * inv2; o4.y = vv[j4].y * inv2;
                o4.z = vv[j4].z * inv2; o4.w = vv[j4].w * inv2;
                *(float4*)&orow[j4 * 256 + lane * 4] = o4;
                *(float4*)&prow[j4 * 256 + lane * 4] = p[sd][j4];   // stash refined
            }
        }
    }
    __syncthreads();

    // ---- loss from LDS (fe rows, refined protos in pl) ----
    // g=0: pos_n(side0) . p_fg ; g=1: neg_n(side1) . p_fg ; g=2: pos_n . p_bg
    for (int pid = w; pid < 360; pid += 16) {
        int g = pid / 120, rr = pid % 120, s = rr / KP, kk = rr % KP;
        const float* A = &fe[((g == 1 ? NS : 0) + s) * CC];
        const float* B = &pl[((g == 2 ? KP : 0) + kk) * CC];
        float acc = 0.f;
#pragma unroll
        for (int j4 = 0; j4 < 3; ++j4) {
            float4 a = *(const float4*)&A[j4 * 256 + lane * 4];
            float4 b = *(const float4*)&B[j4 * 256 + lane * 4];
            acc = fmaf(a.x, b.x, acc); acc = fmaf(a.y, b.y, acc);
            acc = fmaf(a.z, b.z, acc); acc = fmaf(a.w, b.w, acc);
        }
#pragma unroll
        for (int m2 = 1; m2 < 64; m2 <<= 1) acc += __shfl_xor(acc, m2, 64);
        if (lane == 0) dots3[s * 30 + g * 10 + kk] = acc;
    }
    __syncthreads();

    if (tid < NS) {
        const float* d = &dots3[tid * 30];
        float maxp = d[0], maxn = d[10];
#pragma unroll
        for (int k = 1; k < KP; ++k) { maxp = fmaxf(maxp, d[k]); maxn = fmaxf(maxn, d[10 + k]); }
        mp[tid] = maxp; mn[tid] = maxn;

        float x[KP], y[KP];
#pragma unroll
        for (int k = 0; k < KP; ++k) { x[k] = d[k] / 0.07f; y[k] = d[20 + k] / 0.07f; }
        float m10 = x[0];
#pragma unroll
        for (int k = 1; k < KP; ++k) m10 = fmaxf(m10, x[k]);
        float se = 0.f;
#pragma unroll
        for (int k = 0; k < KP; ++k) se += expf(x[k] - m10);
        float numer = logf(se) + m10;
        float m20 = m10;
#pragma unroll
        for (int k = 0; k < KP; ++k) m20 = fmaxf(m20, y[k]);
        float se2 = 0.f;
#pragma unroll
        for (int k = 0; k < KP; ++k) se2 += expf(x[k] - m20);
#pragma unroll
        for (int k = 0; k < KP; ++k) se2 += expf(y[k] - m20);
        float denom = logf(se2) + m20;
        infon[tid] = numer - denom;
    }
    __syncthreads();
    if (tid == 0) {
        float sp = 0.f, sn = 0.f, si = 0.f;
        for (int s = 0; s < NS; ++s) { sp += mp[s]; sn += mn[s]; si += infon[s]; }
        sp /= 12.f; sn /= 12.f; si /= 12.f;
        float loss = fmaxf(0.2f + sn - sp, 0.f) + 0.25f * (-si);
        out[0] = loss;
    }
}

extern "C" void kernel_launch(void* const* d_in, const int* in_sizes, int n_in,
                              void* d_out, int out_size, void* d_ws, size_t ws_size,
                              hipStream_t stream) {
    const float* fg = (const float*)d_in[0];   // [10,768]
    const float* bg = (const float*)d_in[1];   // [10,768]
    const float* F  = (const float*)d_in[2];   // [8,768,64,64]
    const float* M  = (const float*)d_in[3];   // [8,1,64,64]
    float* out = (float*)d_out;                // [1 + 7680 + 7680]

    ull* cand = (ull*)((float*)d_ws + WS_CAND);

    k_scores<<<NBLK, 1024, 0, stream>>>(fg, bg, F, M, cand);
    k_tail  <<<1, 1024, 0, stream>>>(cand, F, fg, bg, out);
}

// Round 16
// 112.943 us; speedup vs baseline: 1.5613x; 1.5613x over previous
//
#include <hip/hip_runtime.h>
#include <math.h>

// Problem constants
#define KP   10      // prototypes per side
#define CC   768     // channels
#define NB   8       // batch
#define HW   4096    // 64*64
#define STOT 32768   // NB*HW
#define NS   12      // N_SAMPLES
#define NBLK 256     // k_scores blocks (128 px each)

// Workspace layout (float offsets)
#define WS_CAND  0       // 2 sides x 256 blocks x 12 u64 = 6144 ull = 12288 floats
#define WS_FEATS 12352   // 24*768 floats (pos 12 rows, then neg 12 rows)
#define WS_PFG   30784   // 10*768
#define WS_PBG   38464   // 10*768

typedef unsigned long long ull;
typedef float f2v __attribute__((ext_vector_type(2)));

// packed 2-wide fma (v_pk_fma_f32); per-component order identical to scalar fmaf
__device__ __forceinline__ f2v fma2(f2v a, float b, f2v c) {
#if __has_builtin(__builtin_elementwise_fma)
    f2v bb = b;
    return __builtin_elementwise_fma(a, bb, c);
#else
    f2v r; r.x = fmaf(a.x, b, c.x); r.y = fmaf(a.y, b, c.y); return r;
#endif
}

// 64-lane sum on the VALU pipe (DPP), replacing LDS-pipe ds_swizzle shuffles.
// Canonical gfx9 sequence; full sum lands in lane 63.
__device__ __forceinline__ float dpp_sum64(float x) {
#define DPP_ADD(ctrl) \
    x += __uint_as_float((unsigned)__builtin_amdgcn_update_dpp(0, (int)__float_as_uint(x), ctrl, 0xf, 0xf, true))
    DPP_ADD(0x111);  // row_shr:1
    DPP_ADD(0x112);  // row_shr:2
    DPP_ADD(0x114);  // row_shr:4
    DPP_ADD(0x118);  // row_shr:8
    DPP_ADD(0x142);  // row_bcast:15
    DPP_ADD(0x143);  // row_bcast:31
#undef DPP_ADD
    return x;        // lane 63 has the total
}
// broadcast lane 63's value to all lanes (uniform SGPR)
__device__ __forceinline__ float bcast63(float x) {
    return __uint_as_float((unsigned)__builtin_amdgcn_readlane((int)__float_as_uint(x), 63));
}

// Order-preserving float->uint map, packed with ~index: exact
// (value desc, index asc) under unsigned max; unique per pixel; 0 = empty.
__device__ __forceinline__ ull pack_key(float v, int idx) {
    unsigned u = __float_as_uint(v);
    u ^= (unsigned)((int)u >> 31) | 0x80000000u;
    return ((ull)u << 32) | (ull)(0xFFFFFFFFu - (unsigned)idx);
}

// ---------------- K1: scores + per-block top-12 candidates ----------------
// (unchanged from R13: packed-f32 accumulators, LDS protos, nt F loads,
//  depth-2 prefetch, barrier-free per-block selection)
__global__ __launch_bounds__(1024) void k_scores(const float* __restrict__ fg,
                                                 const float* __restrict__ bg,
                                                 const float* __restrict__ F,
                                                 const float* __restrict__ M,
                                                 ull* __restrict__ cand) {
    __shared__ float pl[20 * CC];           // 61440 B
    __shared__ float part[8][64][2][21];    // 86016 B
    __shared__ ull kfl[128], kbl[128];      // 2048 B

    const int tid  = threadIdx.x;
    const int w    = __builtin_amdgcn_readfirstlane(tid >> 6);  // wave 0..15
    const int lane = tid & 63;
    const int b    = blockIdx.x;            // 0..255
    const int n    = b >> 5;                // 32 blocks per image
    const int hwb  = (b & 31) * 128 + lane * 2;
    const float* fp = F + ((size_t)n * CC) * HW + hwb;
    const int cbase = w * 48;

    f2v fnA[8], fnB[8];
#pragma unroll
    for (int j = 0; j < 8; ++j)
        fnA[j] = __builtin_nontemporal_load((const f2v*)(fp + (size_t)(cbase + j) * HW));
#pragma unroll
    for (int j = 0; j < 8; ++j)
        fnB[j] = __builtin_nontemporal_load((const f2v*)(fp + (size_t)(cbase + 8 + j) * HW));

    for (int i = tid; i < KP * CC; i += 1024) {
        pl[i]           = fg[i];
        pl[KP * CC + i] = bg[i];
    }
    __syncthreads();

    f2v afg[KP], abg[KP], n2;
#pragma unroll
    for (int k = 0; k < KP; ++k) { afg[k] = 0.f; abg[k] = 0.f; }
    n2 = 0.f;

    for (int c0 = 0; c0 < 48; c0 += 8) {
        f2v f[8];
#pragma unroll
        for (int j = 0; j < 8; ++j) { f[j] = fnA[j]; fnA[j] = fnB[j]; }
        if (c0 + 16 < 48) {
#pragma unroll
            for (int j = 0; j < 8; ++j)
                fnB[j] = __builtin_nontemporal_load((const f2v*)(fp + (size_t)(cbase + c0 + 16 + j) * HW));
        }

#pragma unroll
        for (int k = 0; k < KP; ++k) {
            const float4* pq = (const float4*)&pl[k * CC + cbase + c0];
            float4 a = pq[0], c = pq[1];
            f2v acc = afg[k];
            acc = fma2(f[0], a.x, acc); acc = fma2(f[1], a.y, acc);
            acc = fma2(f[2], a.z, acc); acc = fma2(f[3], a.w, acc);
            acc = fma2(f[4], c.x, acc); acc = fma2(f[5], c.y, acc);
            acc = fma2(f[6], c.z, acc); acc = fma2(f[7], c.w, acc);
            afg[k] = acc;
        }
#pragma unroll
        for (int k = 0; k < KP; ++k) {
            const float4* pq = (const float4*)&pl[(KP + k) * CC + cbase + c0];
            float4 a = pq[0], c = pq[1];
            f2v acc = abg[k];
            acc = fma2(f[0], a.x, acc); acc = fma2(f[1], a.y, acc);
            acc = fma2(f[2], a.z, acc); acc = fma2(f[3], a.w, acc);
            acc = fma2(f[4], c.x, acc); acc = fma2(f[5], c.y, acc);
            acc = fma2(f[6], c.z, acc); acc = fma2(f[7], c.w, acc);
            abg[k] = acc;
        }
#pragma unroll
        for (int j = 0; j < 8; ++j) {
#if __has_builtin(__builtin_elementwise_fma)
            n2 = __builtin_elementwise_fma(f[j], f[j], n2);
#else
            n2.x = fmaf(f[j].x, f[j].x, n2.x); n2.y = fmaf(f[j].y, f[j].y, n2.y);
#endif
        }
    }

    if (w >= 8) {
#pragma unroll
        for (int k = 0; k < KP; ++k) {
            part[w - 8][lane][0][k]      = afg[k].x; part[w - 8][lane][1][k]      = afg[k].y;
            part[w - 8][lane][0][10 + k] = abg[k].x; part[w - 8][lane][1][10 + k] = abg[k].y;
        }
        part[w - 8][lane][0][20] = n2.x; part[w - 8][lane][1][20] = n2.y;
    }
    __syncthreads();
    if (w < 8) {
#pragma unroll
        for (int k = 0; k < KP; ++k) {
            part[w][lane][0][k]      += afg[k].x; part[w][lane][1][k]      += afg[k].y;
            part[w][lane][0][10 + k] += abg[k].x; part[w][lane][1][10 + k] += abg[k].y;
        }
        part[w][lane][0][20] += n2.x; part[w][lane][1][20] += n2.y;
    }
    __syncthreads();

    if (tid < 128) {
        const int lane2 = tid >> 1, j = tid & 1;
        float vals[21];
#pragma unroll
        for (int q = 0; q < 21; ++q) {
            float acc = 0.f;
#pragma unroll
            for (int ss = 0; ss < 8; ++ss) acc += part[ss][lane2][j][q];
            vals[q] = acc;
        }
        float mfg = vals[0], mbg = vals[10];
#pragma unroll
        for (int k = 1; k < KP; ++k) { mfg = fmaxf(mfg, vals[k]); mbg = fmaxf(mbg, vals[10 + k]); }
        float nc = fmaxf(sqrtf(vals[20]), 1e-8f);
        int sp = b * 128 + tid;
        float m = fminf(fmaxf(M[sp], 0.f), 1.f);
        kfl[tid] = pack_key((1.f - mfg / nc) * m, sp);
        kbl[tid] = pack_key((1.f - mbg / nc) * (1.f - m), sp);
    }
    __syncthreads();

    if (w == 0) {
        ull k0 = kfl[lane], k1 = kfl[64 + lane];
        for (int r = 0; r < NS; ++r) {
            ull bk = (k0 > k1) ? k0 : k1;
#pragma unroll
            for (int m2 = 1; m2 < 64; m2 <<= 1) {
                ull o = __shfl_xor(bk, m2, 64);
                bk = (o > bk) ? o : bk;
            }
            if (lane == 0) cand[b * NS + r] = bk;
            if (k0 == bk) k0 = 0ull;
            if (k1 == bk) k1 = 0ull;
        }
    } else if (w == 1) {
        ull k0 = kbl[lane], k1 = kbl[64 + lane];
        for (int r = 0; r < NS; ++r) {
            ull bk = (k0 > k1) ? k0 : k1;
#pragma unroll
            for (int m2 = 1; m2 < 64; m2 <<= 1) {
                ull o = __shfl_xor(bk, m2, 64);
                bk = (o > bk) ? o : bk;
            }
            if (lane == 0) cand[NBLK * NS + b * NS + r] = bk;
            if (k0 == bk) k0 = 0ull;
            if (k1 == bk) k1 = 0ull;
        }
    }
}

// ---- K2: fused global top-12 merge + gather + normalize + refine + blend ----
// (R13 structure; all sum-reductions moved from ds_swizzle shuffles to
//  DPP on the VALU pipe -- LDS pipe left to the ds_read_b128 traffic)
__global__ __launch_bounds__(1024) void k_refine_fused(const ull* __restrict__ cand,
                                                       const float* __restrict__ F,
                                                       const float* __restrict__ fg,
                                                       const float* __restrict__ bg,
                                                       float* __restrict__ pfg,
                                                       float* __restrict__ pbg,
                                                       float* __restrict__ feats,
                                                       float* __restrict__ out) {
    __shared__ float fe[NS * CC];   // 36 KB
    __shared__ int   seli[NS];
    __shared__ float dots[NS][KP];
    __shared__ int   assign[NS];

    const int side = blockIdx.x;
    const int tid  = threadIdx.x;
    const int wave = __builtin_amdgcn_readfirstlane(tid >> 6);  // 0..15
    const int lane = tid & 63;
    const int k    = wave;                                       // proto id for waves<KP
    const float* p0 = (side == 0) ? fg : bg;
    float* pout     = (side == 0) ? pfg : pbg;

    // ---- merge: wave 0 only, no barriers ----
    if (wave == 0) {
        const ull* cs = cand + side * (NBLK * NS);
        ull tv[NS];
#pragma unroll
        for (int q = 0; q < NS; ++q) tv[q] = 0ull;
        for (int c = 0; c < 48; ++c) {               // 3072 keys / 64 lanes
            ull key = cs[c * 64 + lane];
            if (key > tv[NS - 1]) {
#pragma unroll
                for (int q = NS - 1; q >= 1; --q) {
                    bool shift = key > tv[q - 1];
                    bool here  = !shift && (key > tv[q]);
                    tv[q] = shift ? tv[q - 1] : (here ? key : tv[q]);
                }
                if (key > tv[0]) tv[0] = key;
            }
        }
        for (int r = 0; r < NS; ++r) {
            ull bk = tv[0];
#pragma unroll
            for (int m2 = 1; m2 < 64; m2 <<= 1) {
                ull o = __shfl_xor(bk, m2, 64);
                bk = (o > bk) ? o : bk;
            }
            if (lane == 0) seli[r] = (int)(0xFFFFFFFFu - (unsigned)(bk & 0xFFFFFFFFull));
            bool win = (tv[0] == bk);                // keys unique -> one lane
#pragma unroll
            for (int q = 0; q < NS - 1; ++q) tv[q] = win ? tv[q + 1] : tv[q];
            tv[NS - 1] = win ? 0ull : tv[NS - 1];
        }
    }
    __syncthreads();

    // ---- gather 12 rows x 768 channels into LDS ----
    for (int i = tid; i < NS * CC; i += 1024) {
        int srow = i / CC, c = i - srow * CC;
        int sp = seli[srow];
        int nn = sp >> 12, hh = sp & 4095;
        fe[i] = F[((size_t)nn * CC + c) * HW + hh];
    }
    __syncthreads();

    // ---- row-normalize in place: wave r handles row r (DPP sum) ----
    if (wave < NS) {
        float ssq = 0.f;
#pragma unroll
        for (int j = 0; j < 12; ++j) { float v = fe[wave * CC + j * 64 + lane]; ssq = fmaf(v, v, ssq); }
        float tot = bcast63(dpp_sum64(ssq));
        float inv = 1.f / fmaxf(sqrtf(tot), 1e-8f);
#pragma unroll
        for (int j = 0; j < 12; ++j) fe[wave * CC + j * 64 + lane] *= inv;
    }
    __syncthreads();

    // ---- publish normalized feats for k_loss (coalesced b128) ----
    {
        float4* fo = (float4*)(feats + side * (NS * CC));
        const float4* fi = (const float4*)fe;
        for (int i = tid; i < NS * CC / 4; i += 1024) fo[i] = fi[i];
    }

    // ---- refinement: waves 0..9 own proto k; all waves hit barriers ----
    float4 p[3];
#pragma unroll
    for (int j4 = 0; j4 < 3; ++j4) p[j4] = make_float4(0.f, 0.f, 0.f, 0.f);
    if (wave < KP) {
#pragma unroll
        for (int j4 = 0; j4 < 3; ++j4)
            p[j4] = *(const float4*)&p0[k * CC + j4 * 256 + lane * 4];
    }

    for (int it = 0; it < 10; ++it) {
        float step = 0.1f / (1.0f + 0.5f * (float)it);

        if (wave < KP) {
            float d[NS];
#pragma unroll
            for (int s = 0; s < NS; ++s) d[s] = 0.f;
#pragma unroll
            for (int j4 = 0; j4 < 3; ++j4) {
                float4 pv = p[j4];
#pragma unroll
                for (int s = 0; s < NS; ++s) {
                    float4 fv = *(const float4*)&fe[s * CC + j4 * 256 + lane * 4];
                    d[s] = fmaf(fv.x, pv.x, d[s]);
                    d[s] = fmaf(fv.y, pv.y, d[s]);
                    d[s] = fmaf(fv.z, pv.z, d[s]);
                    d[s] = fmaf(fv.w, pv.w, d[s]);
                }
            }
#pragma unroll
            for (int s = 0; s < NS; ++s) d[s] = dpp_sum64(d[s]);   // VALU-pipe reduce
            if (lane == 63) {
#pragma unroll
                for (int s = 0; s < NS; ++s) dots[s][k] = d[s];
            }
        }
        __syncthreads();

        if (tid < NS) {
            float bv = dots[tid][0]; int bk = 0;
#pragma unroll
            for (int kk = 1; kk < KP; ++kk) { float v = dots[tid][kk]; if (v > bv) { bv = v; bk = kk; } }
            assign[tid] = bk;
        }
        __syncthreads();

        if (wave < KP) {
            int a[NS]; int cnt = 0;
#pragma unroll
            for (int s = 0; s < NS; ++s) { a[s] = assign[s]; cnt += (a[s] == k) ? 1 : 0; }

            if (cnt > 0) {
                float4 mac[3];
#pragma unroll
                for (int j4 = 0; j4 < 3; ++j4) mac[j4] = make_float4(0.f, 0.f, 0.f, 0.f);
#pragma unroll
                for (int s = 0; s < NS; ++s) {
                    if (a[s] == k) {   // wave-uniform branch
#pragma unroll
                        for (int j4 = 0; j4 < 3; ++j4) {
                            float4 fv = *(const float4*)&fe[s * CC + j4 * 256 + lane * 4];
                            mac[j4].x += fv.x; mac[j4].y += fv.y; mac[j4].z += fv.z; mac[j4].w += fv.w;
                        }
                    }
                }
                float fcnt = (float)cnt;
                float4 v[3]; float ss = 0.f;
#pragma unroll
                for (int j4 = 0; j4 < 3; ++j4) {
                    v[j4].x = (1.0f - step) * p[j4].x + step * (mac[j4].x / fcnt);
                    v[j4].y = (1.0f - step) * p[j4].y + step * (mac[j4].y / fcnt);
                    v[j4].z = (1.0f - step) * p[j4].z + step * (mac[j4].z / fcnt);
                    v[j4].w = (1.0f - step) * p[j4].w + step * (mac[j4].w / fcnt);
                    ss = fmaf(v[j4].x, v[j4].x, ss);
                    ss = fmaf(v[j4].y, v[j4].y, ss);
                    ss = fmaf(v[j4].z, v[j4].z, ss);
                    ss = fmaf(v[j4].w, v[j4].w, ss);
                }
                float tot = bcast63(dpp_sum64(ss));
                float inv = 1.f / fmaxf(sqrtf(tot), 1e-8f);
#pragma unroll
                for (int j4 = 0; j4 < 3; ++j4) {
                    p[j4].x = v[j4].x * inv; p[j4].y = v[j4].y * inv;
                    p[j4].z = v[j4].z * inv; p[j4].w = v[j4].w * inv;
                }
            }
        }
    }

    if (wave < KP) {
        // publish refined protos for the loss kernel
#pragma unroll
        for (int j4 = 0; j4 < 3; ++j4)
            *(float4*)&pout[k * CC + j4 * 256 + lane * 4] = p[j4];

        // blend epilogue: out row = safe_norm(0.7*p0 + 0.3*p)
        float4 vv[3]; float ss2 = 0.f;
#pragma unroll
        for (int j4 = 0; j4 < 3; ++j4) {
            float4 pz = *(const float4*)&p0[k * CC + j4 * 256 + lane * 4];
            vv[j4].x = 0.7f * pz.x + 0.3f * p[j4].x;
            vv[j4].y = 0.7f * pz.y + 0.3f * p[j4].y;
            vv[j4].z = 0.7f * pz.z + 0.3f * p[j4].z;
            vv[j4].w = 0.7f * pz.w + 0.3f * p[j4].w;
            ss2 = fmaf(vv[j4].x, vv[j4].x, ss2);
            ss2 = fmaf(vv[j4].y, vv[j4].y, ss2);
            ss2 = fmaf(vv[j4].z, vv[j4].z, ss2);
            ss2 = fmaf(vv[j4].w, vv[j4].w, ss2);
        }
        float tot2 = bcast63(dpp_sum64(ss2));
        float inv2 = 1.f / fmaxf(sqrtf(tot2), 1e-8f);
        float* orow = out + 1 + (side * KP + k) * CC;
#pragma unroll
        for (int j4 = 0; j4 < 3; ++j4) {
            float4 o4;
            o4.x = vv[j4].x * inv2; o4.y = vv[j4].y * inv2;
            o4.z = vv[j4].z * inv2; o4.w = vv[j4].w * inv2;
            *(float4*)&orow[j4 * 256 + lane * 4] = o4;
        }
    }
}

// ---------------- K3: loss (1 block, 16 waves; DPP reductions) ----------------
__global__ __launch_bounds__(1024) void k_loss(const float* __restrict__ feats,
                                               const float* __restrict__ pfg,
                                               const float* __restrict__ pbg,
                                               float* __restrict__ out) {
    __shared__ float dots3[NS * 30];   // [s][g*10+k]: g=0 pos@pfg, g=1 neg@pfg, g=2 pos@pbg
    __shared__ float mp[NS], mn[NS], infon[NS];
    int tid = threadIdx.x, wave = tid >> 6, lane = tid & 63;

    for (int pid = wave; pid < 360; pid += 16) {
        int g = pid / 120, rr = pid % 120, s = rr / KP, k = rr % KP;
        const float4* a4 = (const float4*)(feats + ((g == 1 ? NS + s : s) * CC) + lane * 12);
        const float4* b4 = (const float4*)((g == 2 ? pbg : pfg) + k * CC + lane * 12);
        float acc = 0.f;
#pragma unroll
        for (int j = 0; j < 3; ++j) {
            float4 a = a4[j], b = b4[j];
            acc += a.x * b.x + a.y * b.y + a.z * b.z + a.w * b.w;
        }
        acc = dpp_sum64(acc);
        if (lane == 63) dots3[s * 30 + g * 10 + k] = acc;
    }
    __syncthreads();

    if (tid < NS) {
        const float* d = &dots3[tid * 30];
        float maxp = d[0], maxn = d[10];
#pragma unroll
        for (int k = 1; k < KP; ++k) { maxp = fmaxf(maxp, d[k]); maxn = fmaxf(maxn, d[10 + k]); }
        mp[tid] = maxp; mn[tid] = maxn;

        float x[KP], y[KP];
#pragma unroll
        for (int k = 0; k < KP; ++k) { x[k] = d[k] / 0.07f; y[k] = d[20 + k] / 0.07f; }
        float m10 = x[0];
#pragma unroll
        for (int k = 1; k < KP; ++k) m10 = fmaxf(m10, x[k]);
        float se = 0.f;
#pragma unroll
        for (int k = 0; k < KP; ++k) se += expf(x[k] - m10);
        float numer = logf(se) + m10;
        float m20 = m10;
#pragma unroll
        for (int k = 0; k < KP; ++k) m20 = fmaxf(m20, y[k]);
        float se2 = 0.f;
#pragma unroll
        for (int k = 0; k < KP; ++k) se2 += expf(x[k] - m20);
#pragma unroll
        for (int k = 0; k < KP; ++k) se2 += expf(y[k] - m20);
        float denom = logf(se2) + m20;
        infon[tid] = numer - denom;
    }
    __syncthreads();
    if (tid == 0) {
        float sp = 0.f, sn = 0.f, si = 0.f;
        for (int s = 0; s < NS; ++s) { sp += mp[s]; sn += mn[s]; si += infon[s]; }
        sp /= 12.f; sn /= 12.f; si /= 12.f;
        float loss = fmaxf(0.2f + sn - sp, 0.f) + 0.25f * (-si);
        out[0] = loss;
    }
}

extern "C" void kernel_launch(void* const* d_in, const int* in_sizes, int n_in,
                              void* d_out, int out_size, void* d_ws, size_t ws_size,
                              hipStream_t stream) {
    const float* fg = (const float*)d_in[0];   // [10,768]
    const float* bg = (const float*)d_in[1];   // [10,768]
    const float* F  = (const float*)d_in[2];   // [8,768,64,64]
    const float* M  = (const float*)d_in[3];   // [8,1,64,64]
    float* out = (float*)d_out;                // [1 + 7680 + 7680]

    float* w    = (float*)d_ws;
    ull*   cand = (ull*)(w + WS_CAND);
    float* fea  = w + WS_FEATS;
    float* pfg  = w + WS_PFG;
    float* pbg  = w + WS_PBG;

    k_scores      <<<NBLK, 1024, 0, stream>>>(fg, bg, F, M, cand);
    k_refine_fused<<<2, 1024, 0, stream>>>(cand, F, fg, bg, pfg, pbg, fea, out);
    k_loss        <<<1, 1024, 0, stream>>>(fea, pfg, pbg, out);
}

// Round 17
// 112.313 us; speedup vs baseline: 1.5700x; 1.0056x over previous
//
#include <hip/hip_runtime.h>
#include <math.h>

// Problem constants
#define KP   10      // prototypes per side
#define CC   768     // channels
#define NB   8       // batch
#define HW   4096    // 64*64
#define STOT 32768   // NB*HW
#define NS   12      // N_SAMPLES
#define NBLK 256     // k_scores blocks (128 px each)
#define NREG 8       // fe rows cached in registers per proto-wave

// Workspace layout (float offsets)
#define WS_CAND  0       // 2 sides x 256 blocks x 12 u64 = 6144 ull = 12288 floats
#define WS_FEATS 12352   // 24*768 floats (pos 12 rows, then neg 12 rows)
#define WS_PFG   30784   // 10*768
#define WS_PBG   38464   // 10*768

typedef unsigned long long ull;
typedef float f2v __attribute__((ext_vector_type(2)));

// packed 2-wide fma (v_pk_fma_f32); per-component order identical to scalar fmaf
__device__ __forceinline__ f2v fma2(f2v a, float b, f2v c) {
#if __has_builtin(__builtin_elementwise_fma)
    f2v bb = b;
    return __builtin_elementwise_fma(a, bb, c);
#else
    f2v r; r.x = fmaf(a.x, b, c.x); r.y = fmaf(a.y, b, c.y); return r;
#endif
}

// 64-lane sum on the VALU pipe (DPP); full sum lands in lane 63.
__device__ __forceinline__ float dpp_sum64(float x) {
#define DPP_ADD(ctrl) \
    x += __uint_as_float((unsigned)__builtin_amdgcn_update_dpp(0, (int)__float_as_uint(x), ctrl, 0xf, 0xf, true))
    DPP_ADD(0x111);  // row_shr:1
    DPP_ADD(0x112);  // row_shr:2
    DPP_ADD(0x114);  // row_shr:4
    DPP_ADD(0x118);  // row_shr:8
    DPP_ADD(0x142);  // row_bcast:15
    DPP_ADD(0x143);  // row_bcast:31
#undef DPP_ADD
    return x;        // lane 63 has the total
}
// broadcast lane 63's value to all lanes (uniform SGPR)
__device__ __forceinline__ float bcast63(float x) {
    return __uint_as_float((unsigned)__builtin_amdgcn_readlane((int)__float_as_uint(x), 63));
}

// Order-preserving float->uint map, packed with ~index: exact
// (value desc, index asc) under unsigned max; unique per pixel; 0 = empty.
__device__ __forceinline__ ull pack_key(float v, int idx) {
    unsigned u = __float_as_uint(v);
    u ^= (unsigned)((int)u >> 31) | 0x80000000u;
    return ((ull)u << 32) | (ull)(0xFFFFFFFFu - (unsigned)idx);
}

// ---------------- K1: scores + per-block top-12 candidates ----------------
// (unchanged from R16)
__global__ __launch_bounds__(1024) void k_scores(const float* __restrict__ fg,
                                                 const float* __restrict__ bg,
                                                 const float* __restrict__ F,
                                                 const float* __restrict__ M,
                                                 ull* __restrict__ cand) {
    __shared__ float pl[20 * CC];           // 61440 B
    __shared__ float part[8][64][2][21];    // 86016 B
    __shared__ ull kfl[128], kbl[128];      // 2048 B

    const int tid  = threadIdx.x;
    const int w    = __builtin_amdgcn_readfirstlane(tid >> 6);  // wave 0..15
    const int lane = tid & 63;
    const int b    = blockIdx.x;            // 0..255
    const int n    = b >> 5;                // 32 blocks per image
    const int hwb  = (b & 31) * 128 + lane * 2;
    const float* fp = F + ((size_t)n * CC) * HW + hwb;
    const int cbase = w * 48;

    f2v fnA[8], fnB[8];
#pragma unroll
    for (int j = 0; j < 8; ++j)
        fnA[j] = __builtin_nontemporal_load((const f2v*)(fp + (size_t)(cbase + j) * HW));
#pragma unroll
    for (int j = 0; j < 8; ++j)
        fnB[j] = __builtin_nontemporal_load((const f2v*)(fp + (size_t)(cbase + 8 + j) * HW));

    for (int i = tid; i < KP * CC; i += 1024) {
        pl[i]           = fg[i];
        pl[KP * CC + i] = bg[i];
    }
    __syncthreads();

    f2v afg[KP], abg[KP], n2;
#pragma unroll
    for (int k = 0; k < KP; ++k) { afg[k] = 0.f; abg[k] = 0.f; }
    n2 = 0.f;

    for (int c0 = 0; c0 < 48; c0 += 8) {
        f2v f[8];
#pragma unroll
        for (int j = 0; j < 8; ++j) { f[j] = fnA[j]; fnA[j] = fnB[j]; }
        if (c0 + 16 < 48) {
#pragma unroll
            for (int j = 0; j < 8; ++j)
                fnB[j] = __builtin_nontemporal_load((const f2v*)(fp + (size_t)(cbase + c0 + 16 + j) * HW));
        }

#pragma unroll
        for (int k = 0; k < KP; ++k) {
            const float4* pq = (const float4*)&pl[k * CC + cbase + c0];
            float4 a = pq[0], c = pq[1];
            f2v acc = afg[k];
            acc = fma2(f[0], a.x, acc); acc = fma2(f[1], a.y, acc);
            acc = fma2(f[2], a.z, acc); acc = fma2(f[3], a.w, acc);
            acc = fma2(f[4], c.x, acc); acc = fma2(f[5], c.y, acc);
            acc = fma2(f[6], c.z, acc); acc = fma2(f[7], c.w, acc);
            afg[k] = acc;
        }
#pragma unroll
        for (int k = 0; k < KP; ++k) {
            const float4* pq = (const float4*)&pl[(KP + k) * CC + cbase + c0];
            float4 a = pq[0], c = pq[1];
            f2v acc = abg[k];
            acc = fma2(f[0], a.x, acc); acc = fma2(f[1], a.y, acc);
            acc = fma2(f[2], a.z, acc); acc = fma2(f[3], a.w, acc);
            acc = fma2(f[4], c.x, acc); acc = fma2(f[5], c.y, acc);
            acc = fma2(f[6], c.z, acc); acc = fma2(f[7], c.w, acc);
            abg[k] = acc;
        }
#pragma unroll
        for (int j = 0; j < 8; ++j) {
#if __has_builtin(__builtin_elementwise_fma)
            n2 = __builtin_elementwise_fma(f[j], f[j], n2);
#else
            n2.x = fmaf(f[j].x, f[j].x, n2.x); n2.y = fmaf(f[j].y, f[j].y, n2.y);
#endif
        }
    }

    if (w >= 8) {
#pragma unroll
        for (int k = 0; k < KP; ++k) {
            part[w - 8][lane][0][k]      = afg[k].x; part[w - 8][lane][1][k]      = afg[k].y;
            part[w - 8][lane][0][10 + k] = abg[k].x; part[w - 8][lane][1][10 + k] = abg[k].y;
        }
        part[w - 8][lane][0][20] = n2.x; part[w - 8][lane][1][20] = n2.y;
    }
    __syncthreads();
    if (w < 8) {
#pragma unroll
        for (int k = 0; k < KP; ++k) {
            part[w][lane][0][k]      += afg[k].x; part[w][lane][1][k]      += afg[k].y;
            part[w][lane][0][10 + k] += abg[k].x; part[w][lane][1][10 + k] += abg[k].y;
        }
        part[w][lane][0][20] += n2.x; part[w][lane][1][20] += n2.y;
    }
    __syncthreads();

    if (tid < 128) {
        const int lane2 = tid >> 1, j = tid & 1;
        float vals[21];
#pragma unroll
        for (int q = 0; q < 21; ++q) {
            float acc = 0.f;
#pragma unroll
            for (int ss = 0; ss < 8; ++ss) acc += part[ss][lane2][j][q];
            vals[q] = acc;
        }
        float mfg = vals[0], mbg = vals[10];
#pragma unroll
        for (int k = 1; k < KP; ++k) { mfg = fmaxf(mfg, vals[k]); mbg = fmaxf(mbg, vals[10 + k]); }
        float nc = fmaxf(sqrtf(vals[20]), 1e-8f);
        int sp = b * 128 + tid;
        float m = fminf(fmaxf(M[sp], 0.f), 1.f);
        kfl[tid] = pack_key((1.f - mfg / nc) * m, sp);
        kbl[tid] = pack_key((1.f - mbg / nc) * (1.f - m), sp);
    }
    __syncthreads();

    if (w == 0) {
        ull k0 = kfl[lane], k1 = kfl[64 + lane];
        for (int r = 0; r < NS; ++r) {
            ull bk = (k0 > k1) ? k0 : k1;
#pragma unroll
            for (int m2 = 1; m2 < 64; m2 <<= 1) {
                ull o = __shfl_xor(bk, m2, 64);
                bk = (o > bk) ? o : bk;
            }
            if (lane == 0) cand[b * NS + r] = bk;
            if (k0 == bk) k0 = 0ull;
            if (k1 == bk) k1 = 0ull;
        }
    } else if (w == 1) {
        ull k0 = kbl[lane], k1 = kbl[64 + lane];
        for (int r = 0; r < NS; ++r) {
            ull bk = (k0 > k1) ? k0 : k1;
#pragma unroll
            for (int m2 = 1; m2 < 64; m2 <<= 1) {
                ull o = __shfl_xor(bk, m2, 64);
                bk = (o > bk) ? o : bk;
            }
            if (lane == 0) cand[NBLK * NS + b * NS + r] = bk;
            if (k0 == bk) k0 = 0ull;
            if (k1 == bk) k1 = 0ull;
        }
    }
}

// ---- K2: fused merge + gather + normalize + refine + blend ----
// 640 threads = 10 proto-waves. fe rows 0..NREG-1 cached in registers across
// all 10 iterations (fe is loop-invariant); only rows NREG..11 hit the LDS
// pipe inside the loop. Arithmetic bit-identical to R16.
__global__ __launch_bounds__(640) void k_refine_fused(const ull* __restrict__ cand,
                                                      const float* __restrict__ F,
                                                      const float* __restrict__ fg,
                                                      const float* __restrict__ bg,
                                                      float* __restrict__ pfg,
                                                      float* __restrict__ pbg,
                                                      float* __restrict__ feats,
                                                      float* __restrict__ out) {
    __shared__ float fe[NS * CC];   // 36 KB
    __shared__ int   seli[NS];
    __shared__ float dots[NS][KP];
    __shared__ int   assign[NS];

    const int side = blockIdx.x;
    const int tid  = threadIdx.x;
    const int wave = __builtin_amdgcn_readfirstlane(tid >> 6);  // 0..9 (= proto id)
    const int lane = tid & 63;
    const int k    = wave;
    const float* p0 = (side == 0) ? fg : bg;
    float* pout     = (side == 0) ? pfg : pbg;

    // ---- merge: wave 0 only, no barriers ----
    if (wave == 0) {
        const ull* cs = cand + side * (NBLK * NS);
        ull tv[NS];
#pragma unroll
        for (int q = 0; q < NS; ++q) tv[q] = 0ull;
        for (int c = 0; c < 48; ++c) {               // 3072 keys / 64 lanes
            ull key = cs[c * 64 + lane];
            if (key > tv[NS - 1]) {
#pragma unroll
                for (int q = NS - 1; q >= 1; --q) {
                    bool shift = key > tv[q - 1];
                    bool here  = !shift && (key > tv[q]);
                    tv[q] = shift ? tv[q - 1] : (here ? key : tv[q]);
                }
                if (key > tv[0]) tv[0] = key;
            }
        }
        for (int r = 0; r < NS; ++r) {
            ull bk = tv[0];
#pragma unroll
            for (int m2 = 1; m2 < 64; m2 <<= 1) {
                ull o = __shfl_xor(bk, m2, 64);
                bk = (o > bk) ? o : bk;
            }
            if (lane == 0) seli[r] = (int)(0xFFFFFFFFu - (unsigned)(bk & 0xFFFFFFFFull));
            bool win = (tv[0] == bk);                // keys unique -> one lane
#pragma unroll
            for (int q = 0; q < NS - 1; ++q) tv[q] = win ? tv[q + 1] : tv[q];
            tv[NS - 1] = win ? 0ull : tv[NS - 1];
        }
    }
    __syncthreads();

    // ---- gather 12 rows x 768 channels into LDS ----
    for (int i = tid; i < NS * CC; i += 640) {
        int srow = i / CC, c = i - srow * CC;
        int sp = seli[srow];
        int nn = sp >> 12, hh = sp & 4095;
        fe[i] = F[((size_t)nn * CC + c) * HW + hh];
    }
    __syncthreads();

    // ---- row-normalize in place: rows 0..11 over 10 waves (DPP sum) ----
    for (int row = wave; row < NS; row += KP) {
        float ssq = 0.f;
#pragma unroll
        for (int j = 0; j < 12; ++j) { float v = fe[row * CC + j * 64 + lane]; ssq = fmaf(v, v, ssq); }
        float tot = bcast63(dpp_sum64(ssq));
        float inv = 1.f / fmaxf(sqrtf(tot), 1e-8f);
#pragma unroll
        for (int j = 0; j < 12; ++j) fe[row * CC + j * 64 + lane] *= inv;
    }
    __syncthreads();

    // ---- publish normalized feats for k_loss (coalesced b128) ----
    {
        float4* fo = (float4*)(feats + side * (NS * CC));
        const float4* fi = (const float4*)fe;
        for (int i = tid; i < NS * CC / 4; i += 640) fo[i] = fi[i];
    }

    // ---- cache fe rows 0..NREG-1 in registers (loop-invariant) ----
    float4 fer[NREG][3];
#pragma unroll
    for (int s = 0; s < NREG; ++s)
#pragma unroll
        for (int j4 = 0; j4 < 3; ++j4)
            fer[s][j4] = *(const float4*)&fe[s * CC + j4 * 256 + lane * 4];

    // ---- refinement: wave k owns proto k ----
    float4 p[3];
#pragma unroll
    for (int j4 = 0; j4 < 3; ++j4)
        p[j4] = *(const float4*)&p0[k * CC + j4 * 256 + lane * 4];

    for (int it = 0; it < 10; ++it) {
        float step = 0.1f / (1.0f + 0.5f * (float)it);

        float d[NS];
#pragma unroll
        for (int s = 0; s < NS; ++s) d[s] = 0.f;
#pragma unroll
        for (int j4 = 0; j4 < 3; ++j4) {
            float4 pv = p[j4];
#pragma unroll
            for (int s = 0; s < NREG; ++s) {
                float4 fv = fer[s][j4];
                d[s] = fmaf(fv.x, pv.x, d[s]);
                d[s] = fmaf(fv.y, pv.y, d[s]);
                d[s] = fmaf(fv.z, pv.z, d[s]);
                d[s] = fmaf(fv.w, pv.w, d[s]);
            }
#pragma unroll
            for (int s = NREG; s < NS; ++s) {
                float4 fv = *(const float4*)&fe[s * CC + j4 * 256 + lane * 4];
                d[s] = fmaf(fv.x, pv.x, d[s]);
                d[s] = fmaf(fv.y, pv.y, d[s]);
                d[s] = fmaf(fv.z, pv.z, d[s]);
                d[s] = fmaf(fv.w, pv.w, d[s]);
            }
        }
#pragma unroll
        for (int s = 0; s < NS; ++s) d[s] = dpp_sum64(d[s]);   // VALU-pipe reduce
        if (lane == 63) {
#pragma unroll
            for (int s = 0; s < NS; ++s) dots[s][k] = d[s];
        }
        __syncthreads();

        if (tid < NS) {
            float bv = dots[tid][0]; int bk = 0;
#pragma unroll
            for (int kk = 1; kk < KP; ++kk) { float v = dots[tid][kk]; if (v > bv) { bv = v; bk = kk; } }
            assign[tid] = bk;
        }
        __syncthreads();

        int a[NS]; int cnt = 0;
#pragma unroll
        for (int s = 0; s < NS; ++s) { a[s] = assign[s]; cnt += (a[s] == k) ? 1 : 0; }

        if (cnt > 0) {
            float4 mac[3];
#pragma unroll
            for (int j4 = 0; j4 < 3; ++j4) mac[j4] = make_float4(0.f, 0.f, 0.f, 0.f);
#pragma unroll
            for (int s = 0; s < NREG; ++s) {
                if (a[s] == k) {   // wave-uniform branch
#pragma unroll
                    for (int j4 = 0; j4 < 3; ++j4) {
                        float4 fv = fer[s][j4];
                        mac[j4].x += fv.x; mac[j4].y += fv.y; mac[j4].z += fv.z; mac[j4].w += fv.w;
                    }
                }
            }
#pragma unroll
            for (int s = NREG; s < NS; ++s) {
                if (a[s] == k) {
#pragma unroll
                    for (int j4 = 0; j4 < 3; ++j4) {
                        float4 fv = *(const float4*)&fe[s * CC + j4 * 256 + lane * 4];
                        mac[j4].x += fv.x; mac[j4].y += fv.y; mac[j4].z += fv.z; mac[j4].w += fv.w;
                    }
                }
            }
            float fcnt = (float)cnt;
            float4 v[3]; float ss = 0.f;
#pragma unroll
            for (int j4 = 0; j4 < 3; ++j4) {
                v[j4].x = (1.0f - step) * p[j4].x + step * (mac[j4].x / fcnt);
                v[j4].y = (1.0f - step) * p[j4].y + step * (mac[j4].y / fcnt);
                v[j4].z = (1.0f - step) * p[j4].z + step * (mac[j4].z / fcnt);
                v[j4].w = (1.0f - step) * p[j4].w + step * (mac[j4].w / fcnt);
                ss = fmaf(v[j4].x, v[j4].x, ss);
                ss = fmaf(v[j4].y, v[j4].y, ss);
                ss = fmaf(v[j4].z, v[j4].z, ss);
                ss = fmaf(v[j4].w, v[j4].w, ss);
            }
            float tot = bcast63(dpp_sum64(ss));
            float inv = 1.f / fmaxf(sqrtf(tot), 1e-8f);
#pragma unroll
            for (int j4 = 0; j4 < 3; ++j4) {
                p[j4].x = v[j4].x * inv; p[j4].y = v[j4].y * inv;
                p[j4].z = v[j4].z * inv; p[j4].w = v[j4].w * inv;
            }
        }
    }

    // publish refined protos for the loss kernel
#pragma unroll
    for (int j4 = 0; j4 < 3; ++j4)
        *(float4*)&pout[k * CC + j4 * 256 + lane * 4] = p[j4];

    // blend epilogue: out row = safe_norm(0.7*p0 + 0.3*p)
    float4 vv[3]; float ss2 = 0.f;
#pragma unroll
    for (int j4 = 0; j4 < 3; ++j4) {
        float4 pz = *(const float4*)&p0[k * CC + j4 * 256 + lane * 4];
        vv[j4].x = 0.7f * pz.x + 0.3f * p[j4].x;
        vv[j4].y = 0.7f * pz.y + 0.3f * p[j4].y;
        vv[j4].z = 0.7f * pz.z + 0.3f * p[j4].z;
        vv[j4].w = 0.7f * pz.w + 0.3f * p[j4].w;
        ss2 = fmaf(vv[j4].x, vv[j4].x, ss2);
        ss2 = fmaf(vv[j4].y, vv[j4].y, ss2);
        ss2 = fmaf(vv[j4].z, vv[j4].z, ss2);
        ss2 = fmaf(vv[j4].w, vv[j4].w, ss2);
    }
    float tot2 = bcast63(dpp_sum64(ss2));
    float inv2 = 1.f / fmaxf(sqrtf(tot2), 1e-8f);
    float* orow = out + 1 + (side * KP + k) * CC;
#pragma unroll
    for (int j4 = 0; j4 < 3; ++j4) {
        float4 o4;
        o4.x = vv[j4].x * inv2; o4.y = vv[j4].y * inv2;
        o4.z = vv[j4].z * inv2; o4.w = vv[j4].w * inv2;
        *(float4*)&orow[j4 * 256 + lane * 4] = o4;
    }
}

// ---------------- K3: loss (1 block, 16 waves; DPP reductions) ----------------
__global__ __launch_bounds__(1024) void k_loss(const float* __restrict__ feats,
                                               const float* __restrict__ pfg,
                                               const float* __restrict__ pbg,
                                               float* __restrict__ out) {
    __shared__ float dots3[NS * 30];   // [s][g*10+k]: g=0 pos@pfg, g=1 neg@pfg, g=2 pos@pbg
    __shared__ float mp[NS], mn[NS], infon[NS];
    int tid = threadIdx.x, wave = tid >> 6, lane = tid & 63;

    for (int pid = wave; pid < 360; pid += 16) {
        int g = pid / 120, rr = pid % 120, s = rr / KP, k = rr % KP;
        const float4* a4 = (const float4*)(feats + ((g == 1 ? NS + s : s) * CC) + lane * 12);
        const float4* b4 = (const float4*)((g == 2 ? pbg : pfg) + k * CC + lane * 12);
        float acc = 0.f;
#pragma unroll
        for (int j = 0; j < 3; ++j) {
            float4 a = a4[j], b = b4[j];
            acc += a.x * b.x + a.y * b.y + a.z * b.z + a.w * b.w;
        }
        acc = dpp_sum64(acc);
        if (lane == 63) dots3[s * 30 + g * 10 + k] = acc;
    }
    __syncthreads();

    if (tid < NS) {
        const float* d = &dots3[tid * 30];
        float maxp = d[0], maxn = d[10];
#pragma unroll
        for (int k = 1; k < KP; ++k) { maxp = fmaxf(maxp, d[k]); maxn = fmaxf(maxn, d[10 + k]); }
        mp[tid] = maxp; mn[tid] = maxn;

        float x[KP], y[KP];
#pragma unroll
        for (int k = 0; k < KP; ++k) { x[k] = d[k] / 0.07f; y[k] = d[20 + k] / 0.07f; }
        float m10 = x[0];
#pragma unroll
        for (int k = 1; k < KP; ++k) m10 = fmaxf(m10, x[k]);
        float se = 0.f;
#pragma unroll
        for (int k = 0; k < KP; ++k) se += expf(x[k] - m10);
        float numer = logf(se) + m10;
        float m20 = m10;
#pragma unroll
        for (int k = 0; k < KP; ++k) m20 = fmaxf(m20, y[k]);
        float se2 = 0.f;
#pragma unroll
        for (int k = 0; k < KP; ++k) se2 += expf(x[k] - m20);
#pragma unroll
        for (int k = 0; k < KP; ++k) se2 += expf(y[k] - m20);
        float denom = logf(se2) + m20;
        infon[tid] = numer - denom;
    }
    __syncthreads();
    if (tid == 0) {
        float sp = 0.f, sn = 0.f, si = 0.f;
        for (int s = 0; s < NS; ++s) { sp += mp[s]; sn += mn[s]; si += infon[s]; }
        sp /= 12.f; sn /= 12.f; si /= 12.f;
        float loss = fmaxf(0.2f + sn - sp, 0.f) + 0.25f * (-si);
        out[0] = loss;
    }
}

extern "C" void kernel_launch(void* const* d_in, const int* in_sizes, int n_in,
                              void* d_out, int out_size, void* d_ws, size_t ws_size,
                              hipStream_t stream) {
    const float* fg = (const float*)d_in[0];   // [10,768]
    const float* bg = (const float*)d_in[1];   // [10,768]
    const float* F  = (const float*)d_in[2];   // [8,768,64,64]
    const float* M  = (const float*)d_in[3];   // [8,1,64,64]
    float* out = (float*)d_out;                // [1 + 7680 + 7680]

    float* w    = (float*)d_ws;
    ull*   cand = (ull*)(w + WS_CAND);
    float* fea  = w + WS_FEATS;
    float* pfg  = w + WS_PFG;
    float* pbg  = w + WS_PBG;

    k_scores      <<<NBLK, 1024, 0, stream>>>(fg, bg, F, M, cand);
    k_refine_fused<<<2, 640, 0, stream>>>(cand, F, fg, bg, pfg, pbg, fea, out);
    k_loss        <<<1, 1024, 0, stream>>>(fea, pfg, pbg, out);
}

// Round 18
// 111.212 us; speedup vs baseline: 1.5856x; 1.0099x over previous
//
#include <hip/hip_runtime.h>
#include <math.h>

// Problem constants
#define KP   10      // prototypes per side
#define CC   768     // channels
#define NB   8       // batch
#define HW   4096    // 64*64
#define STOT 32768   // NB*HW
#define NS   12      // N_SAMPLES
#define NBLK 256     // k_scores blocks (128 px each)
#define NREG 8       // fe rows cached in registers per proto-wave

// Workspace layout (float offsets)
#define WS_CAND  0       // 2 sides x 256 blocks x 12 u64 = 6144 ull = 12288 floats
#define WS_FEATS 12352   // 24*768 floats (pos 12 rows, then neg 12 rows)
#define WS_PFG   30784   // 10*768
#define WS_PBG   38464   // 10*768

typedef unsigned long long ull;
typedef float f2v __attribute__((ext_vector_type(2)));

// packed 2-wide fma (v_pk_fma_f32); per-component order identical to scalar fmaf
__device__ __forceinline__ f2v fma2(f2v a, float b, f2v c) {
#if __has_builtin(__builtin_elementwise_fma)
    f2v bb = b;
    return __builtin_elementwise_fma(a, bb, c);
#else
    f2v r; r.x = fmaf(a.x, b, c.x); r.y = fmaf(a.y, b, c.y); return r;
#endif
}

// 64-lane sum on the VALU pipe (DPP); full sum lands in lane 63.
__device__ __forceinline__ float dpp_sum64(float x) {
#define DPP_ADD(ctrl) \
    x += __uint_as_float((unsigned)__builtin_amdgcn_update_dpp(0, (int)__float_as_uint(x), ctrl, 0xf, 0xf, true))
    DPP_ADD(0x111);  // row_shr:1
    DPP_ADD(0x112);  // row_shr:2
    DPP_ADD(0x114);  // row_shr:4
    DPP_ADD(0x118);  // row_shr:8
    DPP_ADD(0x142);  // row_bcast:15
    DPP_ADD(0x143);  // row_bcast:31
#undef DPP_ADD
    return x;        // lane 63 has the total
}
// broadcast lane 63's value to all lanes (uniform SGPR)
__device__ __forceinline__ float bcast63(float x) {
    return __uint_as_float((unsigned)__builtin_amdgcn_readlane((int)__float_as_uint(x), 63));
}

// Order-preserving float->uint map, packed with ~index: exact
// (value desc, index asc) under unsigned max; unique per pixel; 0 = empty.
__device__ __forceinline__ ull pack_key(float v, int idx) {
    unsigned u = __float_as_uint(v);
    u ^= (unsigned)((int)u >> 31) | 0x80000000u;
    return ((ull)u << 32) | (ull)(0xFFFFFFFFu - (unsigned)idx);
}

// ---------------- K1: scores + per-block top-12 candidates ----------------
// (unchanged from R16/R17)
__global__ __launch_bounds__(1024) void k_scores(const float* __restrict__ fg,
                                                 const float* __restrict__ bg,
                                                 const float* __restrict__ F,
                                                 const float* __restrict__ M,
                                                 ull* __restrict__ cand) {
    __shared__ float pl[20 * CC];           // 61440 B
    __shared__ float part[8][64][2][21];    // 86016 B
    __shared__ ull kfl[128], kbl[128];      // 2048 B

    const int tid  = threadIdx.x;
    const int w    = __builtin_amdgcn_readfirstlane(tid >> 6);  // wave 0..15
    const int lane = tid & 63;
    const int b    = blockIdx.x;            // 0..255
    const int n    = b >> 5;                // 32 blocks per image
    const int hwb  = (b & 31) * 128 + lane * 2;
    const float* fp = F + ((size_t)n * CC) * HW + hwb;
    const int cbase = w * 48;

    f2v fnA[8], fnB[8];
#pragma unroll
    for (int j = 0; j < 8; ++j)
        fnA[j] = __builtin_nontemporal_load((const f2v*)(fp + (size_t)(cbase + j) * HW));
#pragma unroll
    for (int j = 0; j < 8; ++j)
        fnB[j] = __builtin_nontemporal_load((const f2v*)(fp + (size_t)(cbase + 8 + j) * HW));

    for (int i = tid; i < KP * CC; i += 1024) {
        pl[i]           = fg[i];
        pl[KP * CC + i] = bg[i];
    }
    __syncthreads();

    f2v afg[KP], abg[KP], n2;
#pragma unroll
    for (int k = 0; k < KP; ++k) { afg[k] = 0.f; abg[k] = 0.f; }
    n2 = 0.f;

    for (int c0 = 0; c0 < 48; c0 += 8) {
        f2v f[8];
#pragma unroll
        for (int j = 0; j < 8; ++j) { f[j] = fnA[j]; fnA[j] = fnB[j]; }
        if (c0 + 16 < 48) {
#pragma unroll
            for (int j = 0; j < 8; ++j)
                fnB[j] = __builtin_nontemporal_load((const f2v*)(fp + (size_t)(cbase + c0 + 16 + j) * HW));
        }

#pragma unroll
        for (int k = 0; k < KP; ++k) {
            const float4* pq = (const float4*)&pl[k * CC + cbase + c0];
            float4 a = pq[0], c = pq[1];
            f2v acc = afg[k];
            acc = fma2(f[0], a.x, acc); acc = fma2(f[1], a.y, acc);
            acc = fma2(f[2], a.z, acc); acc = fma2(f[3], a.w, acc);
            acc = fma2(f[4], c.x, acc); acc = fma2(f[5], c.y, acc);
            acc = fma2(f[6], c.z, acc); acc = fma2(f[7], c.w, acc);
            afg[k] = acc;
        }
#pragma unroll
        for (int k = 0; k < KP; ++k) {
            const float4* pq = (const float4*)&pl[(KP + k) * CC + cbase + c0];
            float4 a = pq[0], c = pq[1];
            f2v acc = abg[k];
            acc = fma2(f[0], a.x, acc); acc = fma2(f[1], a.y, acc);
            acc = fma2(f[2], a.z, acc); acc = fma2(f[3], a.w, acc);
            acc = fma2(f[4], c.x, acc); acc = fma2(f[5], c.y, acc);
            acc = fma2(f[6], c.z, acc); acc = fma2(f[7], c.w, acc);
            abg[k] = acc;
        }
#pragma unroll
        for (int j = 0; j < 8; ++j) {
#if __has_builtin(__builtin_elementwise_fma)
            n2 = __builtin_elementwise_fma(f[j], f[j], n2);
#else
            n2.x = fmaf(f[j].x, f[j].x, n2.x); n2.y = fmaf(f[j].y, f[j].y, n2.y);
#endif
        }
    }

    if (w >= 8) {
#pragma unroll
        for (int k = 0; k < KP; ++k) {
            part[w - 8][lane][0][k]      = afg[k].x; part[w - 8][lane][1][k]      = afg[k].y;
            part[w - 8][lane][0][10 + k] = abg[k].x; part[w - 8][lane][1][10 + k] = abg[k].y;
        }
        part[w - 8][lane][0][20] = n2.x; part[w - 8][lane][1][20] = n2.y;
    }
    __syncthreads();
    if (w < 8) {
#pragma unroll
        for (int k = 0; k < KP; ++k) {
            part[w][lane][0][k]      += afg[k].x; part[w][lane][1][k]      += afg[k].y;
            part[w][lane][0][10 + k] += abg[k].x; part[w][lane][1][10 + k] += abg[k].y;
        }
        part[w][lane][0][20] += n2.x; part[w][lane][1][20] += n2.y;
    }
    __syncthreads();

    if (tid < 128) {
        const int lane2 = tid >> 1, j = tid & 1;
        float vals[21];
#pragma unroll
        for (int q = 0; q < 21; ++q) {
            float acc = 0.f;
#pragma unroll
            for (int ss = 0; ss < 8; ++ss) acc += part[ss][lane2][j][q];
            vals[q] = acc;
        }
        float mfg = vals[0], mbg = vals[10];
#pragma unroll
        for (int k = 1; k < KP; ++k) { mfg = fmaxf(mfg, vals[k]); mbg = fmaxf(mbg, vals[10 + k]); }
        float nc = fmaxf(sqrtf(vals[20]), 1e-8f);
        int sp = b * 128 + tid;
        float m = fminf(fmaxf(M[sp], 0.f), 1.f);
        kfl[tid] = pack_key((1.f - mfg / nc) * m, sp);
        kbl[tid] = pack_key((1.f - mbg / nc) * (1.f - m), sp);
    }
    __syncthreads();

    if (w == 0) {
        ull k0 = kfl[lane], k1 = kfl[64 + lane];
        for (int r = 0; r < NS; ++r) {
            ull bk = (k0 > k1) ? k0 : k1;
#pragma unroll
            for (int m2 = 1; m2 < 64; m2 <<= 1) {
                ull o = __shfl_xor(bk, m2, 64);
                bk = (o > bk) ? o : bk;
            }
            if (lane == 0) cand[b * NS + r] = bk;
            if (k0 == bk) k0 = 0ull;
            if (k1 == bk) k1 = 0ull;
        }
    } else if (w == 1) {
        ull k0 = kbl[lane], k1 = kbl[64 + lane];
        for (int r = 0; r < NS; ++r) {
            ull bk = (k0 > k1) ? k0 : k1;
#pragma unroll
            for (int m2 = 1; m2 < 64; m2 <<= 1) {
                ull o = __shfl_xor(bk, m2, 64);
                bk = (o > bk) ? o : bk;
            }
            if (lane == 0) cand[NBLK * NS + b * NS + r] = bk;
            if (k0 == bk) k0 = 0ull;
            if (k1 == bk) k1 = 0ull;
        }
    }
}

// ---------------- K2: merge(redundant) + gather + normalize, 24 blocks ----
// Block b = (side, row). Wave 0 re-merges its side's 3072 candidates (cheap,
// concurrent across blocks) and selects the row-th winner; then 256 threads
// gather that pixel's 768 channels from their own CU (256 loads in flight),
// tree-normalize, and write fea[side*12+row].
__global__ __launch_bounds__(256) void k_gather(const ull* __restrict__ cand,
                                                const float* __restrict__ F,
                                                float* __restrict__ feats) {
    __shared__ int   sel_sh;
    __shared__ float red[256];

    const int b    = blockIdx.x;            // 0..23
    const int side = b / NS, row = b - side * NS;
    const int tid  = threadIdx.x;
    const int wave = tid >> 6, lane = tid & 63;

    if (wave == 0) {
        const ull* cs = cand + side * (NBLK * NS);
        ull tv[NS];
#pragma unroll
        for (int q = 0; q < NS; ++q) tv[q] = 0ull;
        for (int c = 0; c < 48; ++c) {               // 3072 keys / 64 lanes
            ull key = cs[c * 64 + lane];
            if (key > tv[NS - 1]) {
#pragma unroll
                for (int q = NS - 1; q >= 1; --q) {
                    bool shift = key > tv[q - 1];
                    bool here  = !shift && (key > tv[q]);
                    tv[q] = shift ? tv[q - 1] : (here ? key : tv[q]);
                }
                if (key > tv[0]) tv[0] = key;
            }
        }
        ull win = 0ull;
        for (int r = 0; r <= row; ++r) {             // row uniform per block
            ull bk = tv[0];
#pragma unroll
            for (int m2 = 1; m2 < 64; m2 <<= 1) {
                ull o = __shfl_xor(bk, m2, 64);
                bk = (o > bk) ? o : bk;
            }
            if (r == row) win = bk;
            bool w0 = (tv[0] == bk);                 // keys unique -> one lane
#pragma unroll
            for (int q = 0; q < NS - 1; ++q) tv[q] = w0 ? tv[q + 1] : tv[q];
            tv[NS - 1] = w0 ? 0ull : tv[NS - 1];
        }
        if (lane == 0) sel_sh = (int)(0xFFFFFFFFu - (unsigned)(win & 0xFFFFFFFFull));
    }
    __syncthreads();

    const int sp = sel_sh;
    const float* fp = F + ((size_t)(sp >> 12) * CC) * HW + (sp & 4095);
    float v0 = fp[(size_t)(tid)       * HW];
    float v1 = fp[(size_t)(tid + 256) * HW];
    float v2 = fp[(size_t)(tid + 512) * HW];
    red[tid] = v0 * v0 + v1 * v1 + v2 * v2;
    __syncthreads();
    for (int off = 128; off > 0; off >>= 1) { if (tid < off) red[tid] += red[tid + off]; __syncthreads(); }
    float inv = 1.f / fmaxf(sqrtf(red[0]), 1e-8f);
    float* fo = feats + (side * NS + row) * CC;
    fo[tid]       = v0 * inv;
    fo[tid + 256] = v1 * inv;
    fo[tid + 512] = v2 * inv;
}

// ---- K3: refine + blend (2 blocks x 640 = 10 proto-waves) ----
// fea is pre-gathered and normalized; loads are coalesced b128 from L2.
__global__ __launch_bounds__(640) void k_refine(const float* __restrict__ feats,
                                                const float* __restrict__ fg,
                                                const float* __restrict__ bg,
                                                float* __restrict__ pfg,
                                                float* __restrict__ pbg,
                                                float* __restrict__ out) {
    __shared__ float fe[NS * CC];   // 36 KB
    __shared__ float dots[NS][KP];
    __shared__ int   assign[NS];

    const int side = blockIdx.x;
    const int tid  = threadIdx.x;
    const int wave = __builtin_amdgcn_readfirstlane(tid >> 6);  // 0..9 (= proto id)
    const int lane = tid & 63;
    const int k    = wave;
    const float* p0 = (side == 0) ? fg : bg;
    float* pout     = (side == 0) ? pfg : pbg;

    // load normalized feats into LDS (coalesced float4)
    {
        const float4* fi = (const float4*)(feats + side * (NS * CC));
        float4* fl = (float4*)fe;
        for (int i = tid; i < NS * CC / 4; i += 640) fl[i] = fi[i];
    }
    __syncthreads();

    // cache fe rows 0..NREG-1 in registers (loop-invariant)
    float4 fer[NREG][3];
#pragma unroll
    for (int s = 0; s < NREG; ++s)
#pragma unroll
        for (int j4 = 0; j4 < 3; ++j4)
            fer[s][j4] = *(const float4*)&fe[s * CC + j4 * 256 + lane * 4];

    float4 p[3];
#pragma unroll
    for (int j4 = 0; j4 < 3; ++j4)
        p[j4] = *(const float4*)&p0[k * CC + j4 * 256 + lane * 4];

    for (int it = 0; it < 10; ++it) {
        float step = 0.1f / (1.0f + 0.5f * (float)it);

        float d[NS];
#pragma unroll
        for (int s = 0; s < NS; ++s) d[s] = 0.f;
#pragma unroll
        for (int j4 = 0; j4 < 3; ++j4) {
            float4 pv = p[j4];
#pragma unroll
            for (int s = 0; s < NREG; ++s) {
                float4 fv = fer[s][j4];
                d[s] = fmaf(fv.x, pv.x, d[s]);
                d[s] = fmaf(fv.y, pv.y, d[s]);
                d[s] = fmaf(fv.z, pv.z, d[s]);
                d[s] = fmaf(fv.w, pv.w, d[s]);
            }
#pragma unroll
            for (int s = NREG; s < NS; ++s) {
                float4 fv = *(const float4*)&fe[s * CC + j4 * 256 + lane * 4];
                d[s] = fmaf(fv.x, pv.x, d[s]);
                d[s] = fmaf(fv.y, pv.y, d[s]);
                d[s] = fmaf(fv.z, pv.z, d[s]);
                d[s] = fmaf(fv.w, pv.w, d[s]);
            }
        }
#pragma unroll
        for (int s = 0; s < NS; ++s) d[s] = dpp_sum64(d[s]);   // VALU-pipe reduce
        if (lane == 63) {
#pragma unroll
            for (int s = 0; s < NS; ++s) dots[s][k] = d[s];
        }
        __syncthreads();

        if (tid < NS) {
            float bv = dots[tid][0]; int bk = 0;
#pragma unroll
            for (int kk = 1; kk < KP; ++kk) { float v = dots[tid][kk]; if (v > bv) { bv = v; bk = kk; } }
            assign[tid] = bk;
        }
        __syncthreads();

        int a[NS]; int cnt = 0;
#pragma unroll
        for (int s = 0; s < NS; ++s) { a[s] = assign[s]; cnt += (a[s] == k) ? 1 : 0; }

        if (cnt > 0) {
            float4 mac[3];
#pragma unroll
            for (int j4 = 0; j4 < 3; ++j4) mac[j4] = make_float4(0.f, 0.f, 0.f, 0.f);
#pragma unroll
            for (int s = 0; s < NREG; ++s) {
                if (a[s] == k) {   // wave-uniform branch
#pragma unroll
                    for (int j4 = 0; j4 < 3; ++j4) {
                        float4 fv = fer[s][j4];
                        mac[j4].x += fv.x; mac[j4].y += fv.y; mac[j4].z += fv.z; mac[j4].w += fv.w;
                    }
                }
            }
#pragma unroll
            for (int s = NREG; s < NS; ++s) {
                if (a[s] == k) {
#pragma unroll
                    for (int j4 = 0; j4 < 3; ++j4) {
                        float4 fv = *(const float4*)&fe[s * CC + j4 * 256 + lane * 4];
                        mac[j4].x += fv.x; mac[j4].y += fv.y; mac[j4].z += fv.z; mac[j4].w += fv.w;
                    }
                }
            }
            float fcnt = (float)cnt;
            float4 v[3]; float ss = 0.f;
#pragma unroll
            for (int j4 = 0; j4 < 3; ++j4) {
                v[j4].x = (1.0f - step) * p[j4].x + step * (mac[j4].x / fcnt);
                v[j4].y = (1.0f - step) * p[j4].y + step * (mac[j4].y / fcnt);
                v[j4].z = (1.0f - step) * p[j4].z + step * (mac[j4].z / fcnt);
                v[j4].w = (1.0f - step) * p[j4].w + step * (mac[j4].w / fcnt);
                ss = fmaf(v[j4].x, v[j4].x, ss);
                ss = fmaf(v[j4].y, v[j4].y, ss);
                ss = fmaf(v[j4].z, v[j4].z, ss);
                ss = fmaf(v[j4].w, v[j4].w, ss);
            }
            float tot = bcast63(dpp_sum64(ss));
            float inv = 1.f / fmaxf(sqrtf(tot), 1e-8f);
#pragma unroll
            for (int j4 = 0; j4 < 3; ++j4) {
                p[j4].x = v[j4].x * inv; p[j4].y = v[j4].y * inv;
                p[j4].z = v[j4].z * inv; p[j4].w = v[j4].w * inv;
            }
        }
    }

    // publish refined protos for the loss kernel
#pragma unroll
    for (int j4 = 0; j4 < 3; ++j4)
        *(float4*)&pout[k * CC + j4 * 256 + lane * 4] = p[j4];

    // blend epilogue: out row = safe_norm(0.7*p0 + 0.3*p)
    float4 vv[3]; float ss2 = 0.f;
#pragma unroll
    for (int j4 = 0; j4 < 3; ++j4) {
        float4 pz = *(const float4*)&p0[k * CC + j4 * 256 + lane * 4];
        vv[j4].x = 0.7f * pz.x + 0.3f * p[j4].x;
        vv[j4].y = 0.7f * pz.y + 0.3f * p[j4].y;
        vv[j4].z = 0.7f * pz.z + 0.3f * p[j4].z;
        vv[j4].w = 0.7f * pz.w + 0.3f * p[j4].w;
        ss2 = fmaf(vv[j4].x, vv[j4].x, ss2);
        ss2 = fmaf(vv[j4].y, vv[j4].y, ss2);
        ss2 = fmaf(vv[j4].z, vv[j4].z, ss2);
        ss2 = fmaf(vv[j4].w, vv[j4].w, ss2);
    }
    float tot2 = bcast63(dpp_sum64(ss2));
    float inv2 = 1.f / fmaxf(sqrtf(tot2), 1e-8f);
    float* orow = out + 1 + (side * KP + k) * CC;
#pragma unroll
    for (int j4 = 0; j4 < 3; ++j4) {
        float4 o4;
        o4.x = vv[j4].x * inv2; o4.y = vv[j4].y * inv2;
        o4.z = vv[j4].z * inv2; o4.w = vv[j4].w * inv2;
        *(float4*)&orow[j4 * 256 + lane * 4] = o4;
    }
}

// ---------------- K4: loss (1 block, 16 waves; DPP reductions) ----------------
__global__ __launch_bounds__(1024) void k_loss(const float* __restrict__ feats,
                                               const float* __restrict__ pfg,
                                               const float* __restrict__ pbg,
                                               float* __restrict__ out) {
    __shared__ float dots3[NS * 30];   // [s][g*10+k]: g=0 pos@pfg, g=1 neg@pfg, g=2 pos@pbg
    __shared__ float mp[NS], mn[NS], infon[NS];
    int tid = threadIdx.x, wave = tid >> 6, lane = tid & 63;

    for (int pid = wave; pid < 360; pid += 16) {
        int g = pid / 120, rr = pid % 120, s = rr / KP, k = rr % KP;
        const float4* a4 = (const float4*)(feats + ((g == 1 ? NS + s : s) * CC) + lane * 12);
        const float4* b4 = (const float4*)((g == 2 ? pbg : pfg) + k * CC + lane * 12);
        float acc = 0.f;
#pragma unroll
        for (int j = 0; j < 3; ++j) {
            float4 a = a4[j], b = b4[j];
            acc += a.x * b.x + a.y * b.y + a.z * b.z + a.w * b.w;
        }
        acc = dpp_sum64(acc);
        if (lane == 63) dots3[s * 30 + g * 10 + k] = acc;
    }
    __syncthreads();

    if (tid < NS) {
        const float* d = &dots3[tid * 30];
        float maxp = d[0], maxn = d[10];
#pragma unroll
        for (int k = 1; k < KP; ++k) { maxp = fmaxf(maxp, d[k]); maxn = fmaxf(maxn, d[10 + k]); }
        mp[tid] = maxp; mn[tid] = maxn;

        float x[KP], y[KP];
#pragma unroll
        for (int k = 0; k < KP; ++k) { x[k] = d[k] / 0.07f; y[k] = d[20 + k] / 0.07f; }
        float m10 = x[0];
#pragma unroll
        for (int k = 1; k < KP; ++k) m10 = fmaxf(m10, x[k]);
        float se = 0.f;
#pragma unroll
        for (int k = 0; k < KP; ++k) se += expf(x[k] - m10);
        float numer = logf(se) + m10;
        float m20 = m10;
#pragma unroll
        for (int k = 0; k < KP; ++k) m20 = fmaxf(m20, y[k]);
        float se2 = 0.f;
#pragma unroll
        for (int k = 0; k < KP; ++k) se2 += expf(x[k] - m20);
#pragma unroll
        for (int k = 0; k < KP; ++k) se2 += expf(y[k] - m20);
        float denom = logf(se2) + m20;
        infon[tid] = numer - denom;
    }
    __syncthreads();
    if (tid == 0) {
        float sp = 0.f, sn = 0.f, si = 0.f;
        for (int s = 0; s < NS; ++s) { sp += mp[s]; sn += mn[s]; si += infon[s]; }
        sp /= 12.f; sn /= 12.f; si /= 12.f;
        float loss = fmaxf(0.2f + sn - sp, 0.f) + 0.25f * (-si);
        out[0] = loss;
    }
}

extern "C" void kernel_launch(void* const* d_in, const int* in_sizes, int n_in,
                              void* d_out, int out_size, void* d_ws, size_t ws_size,
                              hipStream_t stream) {
    const float* fg = (const float*)d_in[0];   // [10,768]
    const float* bg = (const float*)d_in[1];   // [10,768]
    const float* F  = (const float*)d_in[2];   // [8,768,64,64]
    const float* M  = (const float*)d_in[3];   // [8,1,64,64]
    float* out = (float*)d_out;                // [1 + 7680 + 7680]

    float* w    = (float*)d_ws;
    ull*   cand = (ull*)(w + WS_CAND);
    float* fea  = w + WS_FEATS;
    float* pfg  = w + WS_PFG;
    float* pbg  = w + WS_PBG;

    k_scores<<<NBLK, 1024, 0, stream>>>(fg, bg, F, M, cand);
    k_gather<<<24, 256, 0, stream>>>(cand, F, fea);
    k_refine<<<2, 640, 0, stream>>>(fea, fg, bg, pfg, pbg, out);
    k_loss  <<<1, 1024, 0, stream>>>(fea, pfg, pbg, out);
}